// Round 8
// baseline (80.924 us; speedup 1.0000x reference)
//
#include <hip/hip_runtime.h>
#include <hip/hip_bf16.h>

typedef unsigned short u16;
typedef unsigned int   u32;
typedef __attribute__((ext_vector_type(8))) short bf16x8;
typedef __attribute__((ext_vector_type(4))) float f32x4;

#define NC  256
#define NHW 4096

// ---- LDS layout (bytes) ----
#define OFF_X   0        // u16[64][256] XOR-swizzled: x-tile (alive until out-core) -> OB
#define OFF_AC  32768    // u16[64][64]  XOR-swizzled: A (wave-private rows) then C
#define OFF_ST  40960    // f32[64][4]   ||q||^2 partials
#define OFF_RI  41984    // f32[64]      rinv0 per token
#define SMEM_SZ 42240

__device__ __forceinline__ u16 f2bf_rne(float f) {
  u32 u = __float_as_uint(f);
  return (u16)((u + 0x7FFFu + ((u >> 16) & 1u)) >> 16);
}
__device__ __forceinline__ u16 f2bf(float f) {
  __hip_bfloat16 h = __float2bfloat16(f);
  return *reinterpret_cast<u16*>(&h);
}
__device__ __forceinline__ u32 pack2(float a, float b) {
  return (u32)f2bf(a) | ((u32)f2bf(b) << 16);
}
__device__ __forceinline__ u32 pack2r(float a, float b) {
  return (u32)f2bf_rne(a) | ((u32)f2bf_rne(b) << 16);
}
__device__ __forceinline__ float bf2f(short s) {
  return __uint_as_float(((u32)(unsigned short)s) << 16);
}

// ======================= prepA: wq frags + Wq^T + mem_norm =======================
// blocks 0..31: wq_p frags (M-side layout) + wqT bf16 scatter
// block  32   : rn + mn (normalized mem bank rows, bf16)
__global__ void hop_prepA(const float* __restrict__ wq_f, const float* __restrict__ memb,
                          u16* __restrict__ wq_p, u16* __restrict__ wqT,
                          u16* __restrict__ mn) {
  const int blk = blockIdx.x, tid = threadIdx.x;
  if (blk < 32) {
    int f = (blk << 8) + tid;
    int l = f & 63, g = f >> 6;
    int oi = g & 3, kk = (g >> 2) & 7, w = g >> 5;
    int row = 64*w + 16*oi + (l & 15);
    int col = 32*kk + 8*(l >> 4);
    const float* s = wq_f + (size_t)row * NC + col;
    u16 h[8];
    #pragma unroll
    for (int j = 0; j < 8; ++j) h[j] = f2bf_rne(s[j]);
    uint4 v;
    v.x = (u32)h[0] | ((u32)h[1] << 16);
    v.y = (u32)h[2] | ((u32)h[3] << 16);
    v.z = (u32)h[4] | ((u32)h[5] << 16);
    v.w = (u32)h[6] | ((u32)h[7] << 16);
    *(uint4*)(wq_p + (size_t)f * 8) = v;
    #pragma unroll
    for (int j = 0; j < 8; ++j) wqT[(size_t)(col + j) * NC + row] = h[j];
    return;
  }
  // rn + mn
  __shared__ float part[64][4];
  __shared__ float rn_s[64];
  {
    int m = tid & 63, qd = tid >> 6;
    const float* mr = memb + (size_t)m * NC + qd * 64;
    float s = 0.f;
    #pragma unroll
    for (int i = 0; i < 16; ++i) {
      float4 v = *(const float4*)(mr + 4*i);
      s += v.x*v.x + v.y*v.y + v.z*v.z + v.w*v.w;
    }
    part[m][qd] = s;
  }
  __syncthreads();
  if (tid < 64) {
    float t4 = part[tid][0] + part[tid][1] + part[tid][2] + part[tid][3];
    rn_s[tid] = 1.0f / fmaxf(sqrtf(t4), 1e-12f);
  }
  __syncthreads();
  {
    int m = tid >> 2, seg = tid & 3;
    float rv = rn_s[m];
    const float* src = memb + (size_t)m * NC + seg * 64;
    u16* dst = mn + (size_t)m * NC + seg * 64;
    #pragma unroll
    for (int i = 0; i < 16; ++i) {
      float4 v = *(const float4*)(src + 4*i);
      uint2 p; p.x = pack2r(v.x*rv, v.y*rv); p.y = pack2r(v.z*rv, v.w*rv);
      *(uint2*)(dst + 4*i) = p;
    }
  }
}

// ======= prepB: WW_p, MQ_p, WM_p, G_p frags + wb/pb vectors (contiguous dots) =======
// blocks 0..255: WW (o=blk, c=tid)   256..319: MQ (m=blk-256, c=tid)
// 320..383: WM    384..399: G    400: wb (256)   401: pb (64)
__global__ void hop_prepB(const float* __restrict__ wo_f, const float* __restrict__ bq,
                          const u16* __restrict__ wqT, const u16* __restrict__ mn,
                          u16* __restrict__ WW_p, u16* __restrict__ MQ_p,
                          u16* __restrict__ WM_p, u16* __restrict__ G_p,
                          float* __restrict__ wb_f, float* __restrict__ pb_f) {
  const int blk = blockIdx.x, tid = threadIdx.x;
  if (blk < 256) {          // WW[o][c] = 0.125 * dot(Wout[o][:], Wq[:][c])
    int o = blk, c = tid;
    const float* wr = wo_f + (size_t)o * NC;
    const u16* qt = wqT + (size_t)c * NC;
    float s = 0.f;
    #pragma unroll 8
    for (int i = 0; i < 32; ++i) {
      bf16x8 qv = *(const bf16x8*)(qt + 8*i);
      float4 w0 = *(const float4*)(wr + 8*i);
      float4 w1 = *(const float4*)(wr + 8*i + 4);
      s += w0.x*bf2f(qv[0]) + w0.y*bf2f(qv[1]) + w0.z*bf2f(qv[2]) + w0.w*bf2f(qv[3])
         + w1.x*bf2f(qv[4]) + w1.y*bf2f(qv[5]) + w1.z*bf2f(qv[6]) + w1.w*bf2f(qv[7]);
    }
    int wi = o>>6, oi = (o>>4)&3, kk = c>>5, lgc = (c>>3)&3, j = c&7;
    int li = (lgc<<4) | (o&15);
    WW_p[wi*16384 + kk*2048 + oi*512 + li*8 + j] = f2bf_rne(s * 0.125f);
    return;
  }
  if (blk < 320) {          // MQ[m][c] = dot(mn[m], Wq[:][c])
    int m = blk - 256, c = tid;
    const u16* mr = mn + (size_t)m * NC;
    const u16* qt = wqT + (size_t)c * NC;
    float s = 0.f;
    #pragma unroll 8
    for (int i = 0; i < 32; ++i) {
      bf16x8 mv = *(const bf16x8*)(mr + 8*i);
      bf16x8 qv = *(const bf16x8*)(qt + 8*i);
      #pragma unroll
      for (int j = 0; j < 8; ++j) s += bf2f(mv[j]) * bf2f(qv[j]);
    }
    int mi = m>>4, kk = c>>5, lgc = (c>>3)&3, j = c&7;
    int li = (lgc<<4) | (m&15);
    MQ_p[(kk*4 + mi)*512 + li*8 + j] = f2bf_rne(s);
    return;
  }
  if (blk < 384) {          // WM[o][m] = dot(Wout[o], mn[m])
    int e = ((blk - 320) << 8) + tid;
    int o = e >> 6, m = e & 63;
    const float* wr = wo_f + (size_t)o * NC;
    const u16* mr = mn + (size_t)m * NC;
    float s = 0.f;
    #pragma unroll 8
    for (int i = 0; i < 32; ++i) {
      bf16x8 mv = *(const bf16x8*)(mr + 8*i);
      float4 w0 = *(const float4*)(wr + 8*i);
      float4 w1 = *(const float4*)(wr + 8*i + 4);
      s += w0.x*bf2f(mv[0]) + w0.y*bf2f(mv[1]) + w0.z*bf2f(mv[2]) + w0.w*bf2f(mv[3])
         + w1.x*bf2f(mv[4]) + w1.y*bf2f(mv[5]) + w1.z*bf2f(mv[6]) + w1.w*bf2f(mv[7]);
    }
    int wi = o>>6, oi = (o>>4)&3, kk2 = m>>5, lgc = (m>>3)&3, j = m&7;
    int li = (lgc<<4) | (o&15);
    WM_p[((wi*2 + kk2)*4 + oi)*512 + li*8 + j] = f2bf_rne(s);
    return;
  }
  if (blk < 400) {          // G[m][mp] = dot(mn[m], mn[mp])
    int e = ((blk - 384) << 8) + tid;
    int m = e >> 6, mp = e & 63;
    const u16* ma = mn + (size_t)m * NC;
    const u16* mb2 = mn + (size_t)mp * NC;
    float s = 0.f;
    #pragma unroll 8
    for (int i = 0; i < 32; ++i) {
      bf16x8 av = *(const bf16x8*)(ma + 8*i);
      bf16x8 bv = *(const bf16x8*)(mb2 + 8*i);
      #pragma unroll
      for (int j = 0; j < 8; ++j) s += bf2f(av[j]) * bf2f(bv[j]);
    }
    int mi = m>>4, kk2 = mp>>5, lgc = (mp>>3)&3, j = mp&7;
    int li = (lgc<<4) | (m&15);
    G_p[(kk2*4 + mi)*512 + li*8 + j] = f2bf_rne(s);
    return;
  }
  if (blk == 400) {         // wb[o] = 0.125 * dot(Wout[o], bq)
    const float* wr = wo_f + (size_t)tid * NC;
    float s = 0.f;
    #pragma unroll 8
    for (int i = 0; i < 64; ++i) {
      float4 w0 = *(const float4*)(wr + 4*i);
      float4 b0 = *(const float4*)(bq + 4*i);
      s += w0.x*b0.x + w0.y*b0.y + w0.z*b0.z + w0.w*b0.w;
    }
    wb_f[tid] = s * 0.125f;
    return;
  }
  {                         // pb[m] = dot(mn[m], bq)
    if (tid < 64) {
      const u16* mr = mn + (size_t)tid * NC;
      float s = 0.f;
      #pragma unroll 8
      for (int i = 0; i < 32; ++i) {
        bf16x8 mv = *(const bf16x8*)(mr + 8*i);
        float4 b0 = *(const float4*)(bq + 8*i);
        float4 b1 = *(const float4*)(bq + 8*i + 4);
        s += b0.x*bf2f(mv[0]) + b0.y*bf2f(mv[1]) + b0.z*bf2f(mv[2]) + b0.w*bf2f(mv[3])
           + b1.x*bf2f(mv[4]) + b1.y*bf2f(mv[5]) + b1.z*bf2f(mv[6]) + b1.w*bf2f(mv[7]);
      }
      pb_f[tid] = s;
    }
  }
}

__device__ __forceinline__ void mfma16(const bf16x8 (&mf)[4], const bf16x8 (&nf)[4],
                                       f32x4 (&acc)[4][4]) {
  #pragma unroll
  for (int oi = 0; oi < 4; ++oi)
    #pragma unroll
    for (int ti = 0; ti < 4; ++ti)
      acc[oi][ti] = __builtin_amdgcn_mfma_f32_16x16x32_bf16(mf[oi], nf[ti], acc[oi][ti], 0, 0, 0);
}

// ---- fused main kernel: block = 64 tokens, 4 waves, 3 blocks/CU ----
__global__ __launch_bounds__(256, 3) void hop_main(
    const float* __restrict__ x, const float* __restrict__ bq,
    const float* __restrict__ bout,
    const u16* __restrict__ wq_p, const u16* __restrict__ MQ_p,
    const u16* __restrict__ G_p, const u16* __restrict__ WM_p,
    const u16* __restrict__ WW_p,
    const float* __restrict__ pb_f, const float* __restrict__ wb_f,
    float* __restrict__ out) {
  __shared__ __align__(16) char smem[SMEM_SZ];
  float* StatR = (float*)(smem + OFF_ST);
  float* RinvL = (float*)(smem + OFF_RI);

  const int tid = threadIdx.x;
  const int w  = tid >> 6;
  const int l  = tid & 63;
  const int lg = l >> 4;
  const int ll = l & 15;
  const u32 swz = (u32)((ll & 7) << 4);

  const int bimg = blockIdx.x >> 6;
  const int t0   = (blockIdx.x & 63) * 64;
  const float* xb = x   + (size_t)bimg * NC * NHW + t0;
  float*       ob = out + (size_t)bimg * NC * NHW + t0;

  // ======= T14 split-staging: issue all loads, write half0, overlap half1 =======
  const int tq = tid & 15, cb = tid >> 4;
  float4 xa[8], xv[8];
  #pragma unroll
  for (int j = 0; j < 8; ++j) {
    int cp = cb + 16*j;
    const float* r0 = xb + (size_t)(2*cp) * NHW + 4*tq;
    xa[j] = *(const float4*)r0;
    xv[j] = *(const float4*)(r0 + NHW);
  }
  #pragma unroll
  for (int j = 0; j < 4; ++j) {          // half0: c in [0,128)
    int cp = cb + 16*j;
    #pragma unroll
    for (int i = 0; i < 4; ++i) {
      int t = 4*tq + i;
      *(u32*)(smem + OFF_X + (t << 9) + (((u32)(cp << 2)) ^ (u32)((t & 7) << 4)))
          = pack2((&xa[j].x)[i], (&xv[j].x)[i]);
    }
  }
  __syncthreads();   // b1a: half0 ready

  // ======= GEMM1 (only for ||q||^2): acc = bq + Wq@x =======
  f32x4 acc[4][4];
  #pragma unroll
  for (int oi = 0; oi < 4; ++oi) {
    f32x4 bv = *(const f32x4*)&bq[64*w + 16*oi + 4*lg];
    #pragma unroll
    for (int ti = 0; ti < 4; ++ti) acc[oi][ti] = bv;
  }
  const u16* wqf = wq_p + (size_t)w * 16384 + (size_t)l * 8;
  #pragma unroll
  for (int kk = 0; kk < 4; ++kk) {
    bf16x8 mf[4], nf[4];
    #pragma unroll
    for (int oi = 0; oi < 4; ++oi) mf[oi] = *(const bf16x8*)(wqf + kk*2048 + oi*512);
    #pragma unroll
    for (int ti = 0; ti < 4; ++ti) {
      int row = 16*ti + ll;
      nf[ti] = *(const bf16x8*)(smem + OFF_X + (row << 9) + ((u32)(64*kk + 16*lg) ^ swz));
    }
    mfma16(mf, nf, acc);
  }
  #pragma unroll
  for (int j = 4; j < 8; ++j) {          // half1: c in [128,256)
    int cp = cb + 16*j;
    #pragma unroll
    for (int i = 0; i < 4; ++i) {
      int t = 4*tq + i;
      *(u32*)(smem + OFF_X + (t << 9) + (((u32)(cp << 2)) ^ (u32)((t & 7) << 4)))
          = pack2((&xa[j].x)[i], (&xv[j].x)[i]);
    }
  }
  __syncthreads();   // b1b: full tile ready
  #pragma unroll
  for (int kk = 4; kk < 8; ++kk) {
    bf16x8 mf[4], nf[4];
    #pragma unroll
    for (int oi = 0; oi < 4; ++oi) mf[oi] = *(const bf16x8*)(wqf + kk*2048 + oi*512);
    #pragma unroll
    for (int ti = 0; ti < 4; ++ti) {
      int row = 16*ti + ll;
      nf[ti] = *(const bf16x8*)(smem + OFF_X + (row << 9) + ((u32)(64*kk + 16*lg) ^ swz));
    }
    mfma16(mf, nf, acc);
  }
  // ---- ||q||^2 partials -> StatR ----
  #pragma unroll
  for (int ti = 0; ti < 4; ++ti) {
    float v = 0.f;
    #pragma unroll
    for (int oi = 0; oi < 4; ++oi)
      #pragma unroll
      for (int r = 0; r < 4; ++r) { float e = acc[oi][ti][r]; v += e*e; }
    v += __shfl_xor(v, 16);
    v += __shfl_xor(v, 32);
    if (lg == 0) StatR[(16*ti + ll)*4 + w] = v;
  }

  // ======= P0u = MQ@x + pb (per-wave 16 tokens, reads x LDS) =======
  const int t_own = 16*w + ll;
  const char* xrow = smem + OFF_X + (t_own << 9);
  f32x4 P[4];
  #pragma unroll
  for (int mi = 0; mi < 4; ++mi) P[mi] = *(const f32x4*)&pb_f[16*mi + 4*lg];
  #pragma unroll
  for (int kk = 0; kk < 8; ++kk) {
    bf16x8 nA = *(const bf16x8*)(xrow + ((u32)(64*kk + 16*lg) ^ swz));
    bf16x8 pm[4];
    #pragma unroll
    for (int mi = 0; mi < 4; ++mi) pm[mi] = *(const bf16x8*)(MQ_p + (size_t)((kk*4 + mi)*512) + (size_t)l*8);
    #pragma unroll
    for (int mi = 0; mi < 4; ++mi)
      P[mi] = __builtin_amdgcn_mfma_f32_16x16x32_bf16(pm[mi], nA, P[mi], 0, 0, 0);
  }
  __syncthreads();   // b2: StatR ready
  float rinv0;
  {
    f32x4 p = *(const f32x4*)&StatR[t_own * 4];
    rinv0 = 1.0f / fmaxf(sqrtf(p[0] + p[1] + p[2] + p[3]), 1e-12f);
    if (lg == 0) RinvL[t_own] = rinv0;
  }
  #pragma unroll
  for (int mi = 0; mi < 4; ++mi)
    #pragma unroll
    for (int r = 0; r < 4; ++r) P[mi][r] *= rinv0;

  // ---- preload G fragments ----
  bf16x8 gf[4][2];
  #pragma unroll
  for (int mi = 0; mi < 4; ++mi)
    #pragma unroll
    for (int kk2 = 0; kk2 < 2; ++kk2)
      gf[mi][kk2] = *(const bf16x8*)(G_p + (size_t)((kk2*4 + mi)*512) + (size_t)l*8);

  // ======= 3 Hopfield iterations, fully wave-private =======
  char* ab_row = smem + OFF_AC + (t_own << 7);
  float C[4][4];
  #pragma unroll
  for (int mi = 0; mi < 4; ++mi)
    #pragma unroll
    for (int r = 0; r < 4; ++r) C[mi][r] = 0.f;
  float n2 = 1.0f;

  #pragma unroll
  for (int k = 0; k < 3; ++k) {
    const float wk = (k == 0) ? 0.125f : (k == 1) ? 0.25f : 0.5f;
    float rinv = 1.0f / sqrtf(fmaxf(n2, 1e-24f));
    float sc[4][4];
    float mx = -1e30f;
    #pragma unroll
    for (int mi = 0; mi < 4; ++mi)
      #pragma unroll
      for (int r = 0; r < 4; ++r) { sc[mi][r] = P[mi][r] * rinv; mx = fmaxf(mx, sc[mi][r]); }
    mx = fmaxf(mx, __shfl_xor(mx, 16));
    mx = fmaxf(mx, __shfl_xor(mx, 32));
    float A[4][4];
    float S = 0.f;
    #pragma unroll
    for (int mi = 0; mi < 4; ++mi)
      #pragma unroll
      for (int r = 0; r < 4; ++r) { float e = __expf(sc[mi][r] - mx); A[mi][r] = e; S += e; }
    S += __shfl_xor(S, 16);
    S += __shfl_xor(S, 32);
    float sinv = 1.0f / S;
    float dPA = 0.f;
    #pragma unroll
    for (int mi = 0; mi < 4; ++mi)
      #pragma unroll
      for (int r = 0; r < 4; ++r) {
        A[mi][r] *= sinv;
        dPA += A[mi][r] * P[mi][r];
        C[mi][r] += wk * A[mi][r];
      }
    dPA += __shfl_xor(dPA, 16);
    dPA += __shfl_xor(dPA, 32);
    #pragma unroll
    for (int mi = 0; mi < 4; ++mi) {
      uint2 v; v.x = pack2(A[mi][0], A[mi][1]); v.y = pack2(A[mi][2], A[mi][3]);
      *(uint2*)(ab_row + ((u32)(32*mi + 8*lg) ^ swz)) = v;
    }
    f32x4 V[4];
    #pragma unroll
    for (int mi = 0; mi < 4; ++mi) V[mi] = (f32x4){0.f,0.f,0.f,0.f};
    #pragma unroll
    for (int kk2 = 0; kk2 < 2; ++kk2) {
      bf16x8 nf = *(const bf16x8*)(ab_row + ((u32)(64*kk2 + 16*lg) ^ swz));
      #pragma unroll
      for (int mi = 0; mi < 4; ++mi)
        V[mi] = __builtin_amdgcn_mfma_f32_16x16x32_bf16(gf[mi][kk2], nf, V[mi], 0, 0, 0);
    }
    float dVA = 0.f;
    #pragma unroll
    for (int mi = 0; mi < 4; ++mi)
      #pragma unroll
      for (int r = 0; r < 4; ++r) {
        dVA += A[mi][r] * V[mi][r];
        P[mi][r] = 0.5f * (P[mi][r] + V[mi][r]);
      }
    dVA += __shfl_xor(dVA, 16);
    dVA += __shfl_xor(dVA, 32);
    n2 = 0.25f * n2 + 0.5f * dPA + 0.25f * dVA;
  }

  // ---- C -> AC LDS bf16 ----
  #pragma unroll
  for (int mi = 0; mi < 4; ++mi) {
    uint2 v; v.x = pack2(C[mi][0], C[mi][1]); v.y = pack2(C[mi][2], C[mi][3]);
    *(uint2*)(ab_row + ((u32)(32*mi + 8*lg) ^ swz)) = v;
  }
  __syncthreads();   // b3: C + RinvL ready

  // ======= out-core: rinv0*(WW@x + wb) + bout + WM@C  (WW,wb pre-scaled 0.125) =======
  #pragma unroll
  for (int oi = 0; oi < 4; ++oi) {
    f32x4 wv = *(const f32x4*)&wb_f[64*w + 16*oi + 4*lg];
    #pragma unroll
    for (int ti = 0; ti < 4; ++ti) acc[oi][ti] = wv;
  }
  {
    const u16* wwf = WW_p + (size_t)w * 16384 + (size_t)l * 8;
    #pragma unroll
    for (int kk = 0; kk < 8; ++kk) {
      bf16x8 mf[4], nf[4];
      #pragma unroll
      for (int oi = 0; oi < 4; ++oi) mf[oi] = *(const bf16x8*)(wwf + kk*2048 + oi*512);
      #pragma unroll
      for (int ti = 0; ti < 4; ++ti) {
        int row = 16*ti + ll;
        nf[ti] = *(const bf16x8*)(smem + OFF_X + (row << 9) + ((u32)(64*kk + 16*lg) ^ swz));
      }
      mfma16(mf, nf, acc);
    }
  }
  #pragma unroll
  for (int ti = 0; ti < 4; ++ti) {
    float rv = RinvL[16*ti + ll];
    #pragma unroll
    for (int oi = 0; oi < 4; ++oi)
      #pragma unroll
      for (int r = 0; r < 4; ++r) acc[oi][ti][r] *= rv;
  }
  #pragma unroll
  for (int oi = 0; oi < 4; ++oi) {
    f32x4 bv = *(const f32x4*)&bout[64*w + 16*oi + 4*lg];
    #pragma unroll
    for (int ti = 0; ti < 4; ++ti)
      #pragma unroll
      for (int r = 0; r < 4; ++r) acc[oi][ti][r] += bv[r];
  }
  #pragma unroll
  for (int kk2 = 0; kk2 < 2; ++kk2) {
    bf16x8 wmf[4], nfc[4];
    #pragma unroll
    for (int oi = 0; oi < 4; ++oi)
      wmf[oi] = *(const bf16x8*)(WM_p + (size_t)(((w*2 + kk2)*4 + oi)*512) + (size_t)l*8);
    #pragma unroll
    for (int ti = 0; ti < 4; ++ti)
      nfc[ti] = *(const bf16x8*)(smem + OFF_AC + ((16*ti + ll) << 7) + ((u32)(64*kk2 + 16*lg) ^ swz));
    mfma16(wmf, nfc, acc);
  }
  __syncthreads();   // b4: x-tile and AC reads done

  // ======= epilogue: per-wave LDS transpose (overwrites x region), coalesced I/O =======
  {
    char* OB = smem + OFF_X + ((u32)w << 13);   // f32[32][64], XOR-swizzled
    #pragma unroll
    for (int h = 0; h < 2; ++h) {
      __builtin_amdgcn_sched_barrier(0);
      #pragma unroll
      for (int q = 0; q < 2; ++q) {
        int oi = 2*h + q;
        #pragma unroll
        for (int ti = 0; ti < 4; ++ti)
          #pragma unroll
          for (int r = 0; r < 4; ++r) {
            int o_loc = 16*q + 4*lg + r;
            int t = 16*ti + ll;
            *(float*)(OB + (o_loc << 8) + ((u32)(t << 2) ^ (u32)((o_loc & 7) << 4)))
                = acc[oi][ti][r];
          }
      }
      __builtin_amdgcn_sched_barrier(0);
      #pragma unroll
      for (int s = 0; s < 8; ++s) {
        int o_loc = 4*s + lg;
        int o = 64*w + 32*h + o_loc;
        f32x4 v = *(const f32x4*)(OB + (o_loc << 8)
                                  + ((u32)(16*ll) ^ (u32)((o_loc & 7) << 4)));
        float4 vx = *(const float4*)(xb + (size_t)o * NHW + 4*ll);
        float4 vo = { v[0] + vx.x, v[1] + vx.y, v[2] + vx.z, v[3] + vx.w };
        *(float4*)(ob + (size_t)o * NHW + 4*ll) = vo;
      }
    }
  }
}

extern "C" void kernel_launch(void* const* d_in, const int* in_sizes, int n_in,
                              void* d_out, int out_size, void* d_ws, size_t ws_size,
                              hipStream_t stream) {
  const float* x    = (const float*)d_in[0];
  const float* memb = (const float*)d_in[1];
  const float* Wq   = (const float*)d_in[2];
  const float* bq   = (const float*)d_in[3];
  const float* Wout = (const float*)d_in[4];
  const float* bout = (const float*)d_in[5];
  float* out = (float*)d_out;

  u16* wq_p = (u16*)d_ws;             // 65536 u16
  u16* wqT  = wq_p + 65536;           // 65536
  u16* mn   = wq_p + 131072;          // 16384
  u16* G_p  = wq_p + 147456;          // 4096
  u16* WM_p = wq_p + 151552;          // 16384
  u16* WW_p = wq_p + 167936;          // 65536
  u16* MQ_p = wq_p + 233472;          // 16384
  float* pb_f = (float*)(wq_p + 249856);   // 64 f32 (16B aligned)
  float* wb_f = pb_f + 64;                 // 256 f32

  hop_prepA<<<33, 256, 0, stream>>>(Wq, memb, wq_p, wqT, mn);
  hop_prepB<<<402, 256, 0, stream>>>(Wout, bq, wqT, mn, WW_p, MQ_p, WM_p, G_p, wb_f, pb_f);
  hop_main<<<1024, 256, 0, stream>>>(x, bq, bout, wq_p, MQ_p, G_p, WM_p, WW_p, pb_f, wb_f, out);
}